// Round 1
// baseline (162.548 us; speedup 1.0000x reference)
//
#include <hip/hip_runtime.h>

#define IN_FEATURES 212445
#define N1 65536
#define N2 16384
#define NCLS 20
#define BATCH 32

// ws layout (bytes):
//  t3      : float[32*128]  @ 0       (16384 B)   -- zeroed each call
//  c2i     : int[128]       @ 16384               -- zeroed each call
//  cnt2i   : int[128]       @ 16896               -- zeroed each call
//  u1      : float[64]      @ 17408
//  v1      : float[64]      @ 17664
//  u2      : float[128]     @ 17920
//  v2      : float[128]     @ 18432
//  w2      : float[128]     @ 18944
//  A       : float[20*128]  @ 19456
//  constv  : float[20]      @ 29696

// Setup: block 0 computes chain weights u1,v1,u2,v2,w2; blocks 1..8 build
// the two 128-bin count histograms (c2 over 65536 j's, cnt2 over 16384 k's).
__global__ __launch_bounds__(256) void k_setup(
    const float* __restrict__ W0, const float* __restrict__ b0,
    const float* __restrict__ W1, const float* __restrict__ b1,
    const float* __restrict__ W2,
    const int* __restrict__ p1, const int* __restrict__ p2,
    int* __restrict__ c2i, int* __restrict__ cnt2i,
    float* __restrict__ u1, float* __restrict__ v1,
    float* __restrict__ u2, float* __restrict__ v2, float* __restrict__ w2)
{
    int t = threadIdx.x;
    if (blockIdx.x == 0) {
        __shared__ float su1[64], sv1[64];
        if (t < 64) {
            float a = 0.f, b = 0.f;
            for (int c = 0; c < 32; ++c) {
                float w = W1[t * 32 + c];
                a += w * W0[c];        // W0 is (32,1)
                b += w * b0[c];
            }
            su1[t] = a; sv1[t] = b;
            u1[t] = a; v1[t] = b;
        }
        __syncthreads();
        if (t < 128) {
            float a = 0.f, b = 0.f, c = 0.f;
            for (int j = 0; j < 64; ++j) {
                float w = W2[t * 64 + j];
                a += w * su1[j];
                b += w * sv1[j];
                c += w * b1[j];
            }
            u2[t] = a; v2[t] = b; w2[t] = c;
        }
    } else {
        __shared__ int hA[128], hB[128];
        if (t < 128) { hA[t] = 0; hB[t] = 0; }
        __syncthreads();
        const int total = N1 + N2;
        const int stride = (gridDim.x - 1) * blockDim.x;
        for (int idx = (blockIdx.x - 1) * blockDim.x + t; idx < total; idx += stride) {
            if (idx < N1) {
                int m = p2[p1[idx]];
                atomicAdd(&hA[m], 1);
            } else {
                int m = p2[idx - N1];
                atomicAdd(&hB[m], 1);
            }
        }
        __syncthreads();
        if (t < 128)      atomicAdd(&c2i[t], hA[t]);
        else              atomicAdd(&cnt2i[t - 128], hB[t - 128]);
    }
}

// t3[n,m] = sum over leaves i with p2[p1[p0[i]]]==m of x[n,i].
// Grid: 512 blocks = 4 row-groups (8 batch rows each) x 128 i-chunks.
__global__ __launch_bounds__(256) void k_t3(
    const float* __restrict__ x,
    const int* __restrict__ p0, const int* __restrict__ p1,
    const int* __restrict__ p2, float* __restrict__ t3)
{
    __shared__ float acc[8 * 128];
    int t = threadIdx.x;
    for (int s = t; s < 1024; s += 256) acc[s] = 0.f;
    __syncthreads();

    int g  = blockIdx.x & 3;   // row group: rows [8g, 8g+8)
    int cb = blockIdx.x >> 2;  // i-chunk block 0..127
    int base_row = g * 8;

    for (int i = cb * 256 + t; i < IN_FEATURES; i += 128 * 256) {
        int m = p2[p1[p0[i]]];
        const float* xp = x + i;
        #pragma unroll
        for (int r = 0; r < 8; ++r) {
            float v = xp[(base_row + r) * IN_FEATURES];
            atomicAdd(&acc[r * 128 + m], v);
        }
    }
    __syncthreads();
    for (int s = t; s < 1024; s += 256) {
        int r = s >> 7, m = s & 127;
        atomicAdd(&t3[(base_row + r) * 128 + m], acc[s]);
    }
}

// A[cls,m] = sum_o fc_w[cls, o*128+m] * u2[o]
// const[cls] = fc_b[cls] + sum_m ( c2[m]*Sv + cnt2[m]*Sw + Sb )
__global__ __launch_bounds__(128) void k_A(
    const float* __restrict__ fc_w, const float* __restrict__ fc_b,
    const float* __restrict__ b2,
    const float* __restrict__ u2, const float* __restrict__ v2,
    const float* __restrict__ w2,
    const int* __restrict__ c2i, const int* __restrict__ cnt2i,
    float* __restrict__ A, float* __restrict__ constv)
{
    __shared__ float su[128], sv[128], sw[128], sb[128];
    __shared__ float red[128];
    int m = threadIdx.x;  // 128 threads
    su[m] = u2[m]; sv[m] = v2[m]; sw[m] = w2[m]; sb[m] = b2[m];
    __syncthreads();

    int cls = blockIdx.x;
    const float* fw = fc_w + cls * 16384 + m;
    float Sa = 0.f, Sv = 0.f, Sw = 0.f, Sb = 0.f;
    for (int o = 0; o < 128; ++o) {
        float w = fw[o * 128];
        Sa += w * su[o];
        Sv += w * sv[o];
        Sw += w * sw[o];
        Sb += w * sb[o];
    }
    A[cls * 128 + m] = Sa;
    red[m] = (float)c2i[m] * Sv + (float)cnt2i[m] * Sw + Sb;
    __syncthreads();
    for (int s = 64; s > 0; s >>= 1) {
        if (m < s) red[m] += red[m + s];
        __syncthreads();
    }
    if (m == 0) constv[cls] = red[0] + fc_b[cls];
}

// logits[n,cls] = const[cls] + sum_m A[cls,m] * t3[n,m]
__global__ __launch_bounds__(640) void k_logits(
    const float* __restrict__ t3, const float* __restrict__ A,
    const float* __restrict__ constv, float* __restrict__ out)
{
    int tid = threadIdx.x;
    if (tid < BATCH * NCLS) {
        int n = tid / NCLS, cls = tid % NCLS;
        const float* tr = t3 + n * 128;
        const float* ar = A + cls * 128;
        float s = constv[cls];
        for (int m = 0; m < 128; ++m) s += ar[m] * tr[m];
        out[n * NCLS + cls] = s;
    }
}

extern "C" void kernel_launch(void* const* d_in, const int* in_sizes, int n_in,
                              void* d_out, int out_size, void* d_ws, size_t ws_size,
                              hipStream_t stream)
{
    const float* x    = (const float*)d_in[0];
    const float* W0   = (const float*)d_in[1];
    const float* b0   = (const float*)d_in[2];
    const float* W1   = (const float*)d_in[3];
    const float* b1   = (const float*)d_in[4];
    const float* W2   = (const float*)d_in[5];
    const float* b2   = (const float*)d_in[6];
    const float* fc_w = (const float*)d_in[7];
    const float* fc_b = (const float*)d_in[8];
    const int*   p0   = (const int*)d_in[9];
    const int*   p1   = (const int*)d_in[10];
    const int*   p2   = (const int*)d_in[11];

    char* ws = (char*)d_ws;
    float* t3     = (float*)(ws + 0);
    int*   c2i    = (int*)(ws + 16384);
    int*   cnt2i  = (int*)(ws + 16896);
    float* u1     = (float*)(ws + 17408);
    float* v1     = (float*)(ws + 17664);
    float* u2     = (float*)(ws + 17920);
    float* v2     = (float*)(ws + 18432);
    float* w2     = (float*)(ws + 18944);
    float* A      = (float*)(ws + 19456);
    float* constv = (float*)(ws + 29696);

    // zero t3 + c2i + cnt2i (ws is poisoned 0xAA before every call)
    hipMemsetAsync(ws, 0, 17408, stream);

    k_setup<<<9, 256, 0, stream>>>(W0, b0, W1, b1, W2, p1, p2,
                                   c2i, cnt2i, u1, v1, u2, v2, w2);
    k_t3<<<512, 256, 0, stream>>>(x, p0, p1, p2, t3);
    k_A<<<20, 128, 0, stream>>>(fc_w, fc_b, b2, u2, v2, w2, c2i, cnt2i, A, constv);
    k_logits<<<1, 640, 0, stream>>>(t3, A, constv, (float*)d_out);
}

// Round 2
// 154.870 us; speedup vs baseline: 1.0496x; 1.0496x over previous
//
#include <hip/hip_runtime.h>

#define IN_FEATURES 212445
#define N1 65536
#define N2 16384
#define NCLS 20
#define BATCH 32
#define HIST_BLOCKS 16

// ws layout (bytes):
//  t3   : float[32*128]        @ 0      (16384 B)  -- zeroed by k_setup block 1
//  hist : int[16][256]         @ 16384  (16384 B)  -- per-block partials, no zeroing needed
//  u2   : float[128]           @ 32768
//  v2   : float[128]           @ 33280
//  w2   : float[128]           @ 33792

// k_setup, grid = 18 blocks x 256:
//   block 0      : chain weights u2 = W2*W1*W0, v2 = W2*W1*b0, w2 = W2*b1
//   block 1      : zero t3 (4096 floats)
//   blocks 2..17 : per-block count histograms -> hist[b-2][0..127]=c2 part,
//                  hist[b-2][128..255]=cnt2 part (written, not atomically added)
__global__ __launch_bounds__(256) void k_setup(
    const float* __restrict__ W0, const float* __restrict__ b0,
    const float* __restrict__ W1, const float* __restrict__ b1,
    const float* __restrict__ W2,
    const int* __restrict__ p1, const int* __restrict__ p2,
    float* __restrict__ t3, int* __restrict__ hist,
    float* __restrict__ u2, float* __restrict__ v2, float* __restrict__ w2)
{
    int t = threadIdx.x;
    int b = blockIdx.x;
    if (b == 0) {
        __shared__ float su1[64], sv1[64];
        if (t < 64) {
            float a = 0.f, bb = 0.f;
            for (int c = 0; c < 32; ++c) {
                float w = W1[t * 32 + c];
                a  += w * W0[c];      // W0 is (32,1)
                bb += w * b0[c];
            }
            su1[t] = a; sv1[t] = bb;
        }
        __syncthreads();
        if (t < 128) {
            float a = 0.f, bb = 0.f, c = 0.f;
            for (int j = 0; j < 64; ++j) {
                float w = W2[t * 64 + j];
                a  += w * su1[j];
                bb += w * sv1[j];
                c  += w * b1[j];
            }
            u2[t] = a; v2[t] = bb; w2[t] = c;
        }
    } else if (b == 1) {
        for (int s = t; s < BATCH * 128; s += 256) t3[s] = 0.f;
    } else {
        __shared__ int hA[128], hB[128];
        if (t < 128) { hA[t] = 0; hB[t] = 0; }
        __syncthreads();
        const int total = N1 + N2;
        const int stride = HIST_BLOCKS * 256;
        for (int idx = (b - 2) * 256 + t; idx < total; idx += stride) {
            if (idx < N1) atomicAdd(&hA[p2[p1[idx]]], 1);
            else          atomicAdd(&hB[p2[idx - N1]], 1);
        }
        __syncthreads();
        hist[(b - 2) * 256 + t] = (t < 128) ? hA[t] : hB[t - 128];
    }
}

// t3[n,m] = sum over leaves i with p2[p1[p0[i]]]==m of x[n,i].
// Each block handles a strided slice of i for ALL 32 batch rows, so the
// parent chain is gathered exactly once per leaf. acc = 16 KB LDS.
__global__ __launch_bounds__(256) void k_t3(
    const float* __restrict__ x,
    const int* __restrict__ p0, const int* __restrict__ p1,
    const int* __restrict__ p2, float* __restrict__ t3)
{
    __shared__ float acc[BATCH * 128];
    int t = threadIdx.x;
    for (int s = t; s < BATCH * 128; s += 256) acc[s] = 0.f;
    __syncthreads();

    for (int i = blockIdx.x * 256 + t; i < IN_FEATURES; i += 256 * 256) {
        int m = p2[p1[p0[i]]];
        const float* xp = x + i;
        #pragma unroll
        for (int r = 0; r < BATCH; ++r) {
            atomicAdd(&acc[r * 128 + m], xp[r * IN_FEATURES]);
        }
    }
    __syncthreads();
    for (int s = t; s < BATCH * 128; s += 256)
        atomicAdd(&t3[s], acc[s]);
}

// k_final, grid = 20 blocks (one per class) x 128 threads:
//   Sa[m]  = sum_o fc_w[cls, o*128+m] * u2[o]        (= A[cls,m])
//   const  = fc_b[cls] + sum_m ( c2[m]*Sv[m] + cnt2[m]*Sw[m] + Sb[m] )
//   out[n,cls] = const + sum_m Sa[m] * t3[n,m]
__global__ __launch_bounds__(128) void k_final(
    const float* __restrict__ fc_w, const float* __restrict__ fc_b,
    const float* __restrict__ b2,
    const float* __restrict__ u2, const float* __restrict__ v2,
    const float* __restrict__ w2,
    const int* __restrict__ hist, const float* __restrict__ t3,
    float* __restrict__ out)
{
    __shared__ float su[128], sv[128], sw[128], sb[128];
    __shared__ float sA[128], red[128];
    __shared__ float st3[BATCH * 129];   // +1 pad: read conflicts <= 4-way
    __shared__ float sconst;
    int m = threadIdx.x;   // 128 threads
    int cls = blockIdx.x;

    su[m] = u2[m]; sv[m] = v2[m]; sw[m] = w2[m]; sb[m] = b2[m];
    // load t3 tile (coalesced global, padded LDS rows)
    for (int s = m; s < BATCH * 128; s += 128) {
        int r = s >> 7, mm = s & 127;
        st3[r * 129 + mm] = t3[s];
    }
    // reduce histogram partials
    int c2 = 0, cn2 = 0;
    #pragma unroll
    for (int h = 0; h < HIST_BLOCKS; ++h) {
        c2  += hist[h * 256 + m];
        cn2 += hist[h * 256 + 128 + m];
    }
    __syncthreads();

    const float* fw = fc_w + cls * 16384 + m;
    float Sa = 0.f, Sv = 0.f, Sw = 0.f, Sb = 0.f;
    #pragma unroll 4
    for (int o = 0; o < 128; ++o) {
        float w = fw[o * 128];
        Sa += w * su[o];
        Sv += w * sv[o];
        Sw += w * sw[o];
        Sb += w * sb[o];
    }
    sA[m] = Sa;
    red[m] = (float)c2 * Sv + (float)cn2 * Sw + Sb;
    __syncthreads();
    for (int s = 64; s > 0; s >>= 1) {
        if (m < s) red[m] += red[m + s];
        __syncthreads();
    }
    if (m == 0) sconst = red[0] + fc_b[cls];
    __syncthreads();

    // 32 dot products of length 128: thread t -> (n = t>>2, quarter q = t&3)
    int n = m >> 2, q = m & 3;
    const float* tr = st3 + n * 129 + q * 32;
    const float* ar = sA + q * 32;
    float s = 0.f;
    #pragma unroll
    for (int k = 0; k < 32; ++k) s += ar[k] * tr[k];
    red[m] = s;
    __syncthreads();
    if (q == 0)
        out[n * NCLS + cls] = sconst + red[m] + red[m + 1] + red[m + 2] + red[m + 3];
}

extern "C" void kernel_launch(void* const* d_in, const int* in_sizes, int n_in,
                              void* d_out, int out_size, void* d_ws, size_t ws_size,
                              hipStream_t stream)
{
    const float* x    = (const float*)d_in[0];
    const float* W0   = (const float*)d_in[1];
    const float* b0   = (const float*)d_in[2];
    const float* W1   = (const float*)d_in[3];
    const float* b1   = (const float*)d_in[4];
    const float* W2   = (const float*)d_in[5];
    const float* b2   = (const float*)d_in[6];
    const float* fc_w = (const float*)d_in[7];
    const float* fc_b = (const float*)d_in[8];
    const int*   p0   = (const int*)d_in[9];
    const int*   p1   = (const int*)d_in[10];
    const int*   p2   = (const int*)d_in[11];

    char* ws = (char*)d_ws;
    float* t3   = (float*)(ws + 0);
    int*   hist = (int*)(ws + 16384);
    float* u2   = (float*)(ws + 32768);
    float* v2   = (float*)(ws + 33280);
    float* w2   = (float*)(ws + 33792);

    k_setup<<<2 + HIST_BLOCKS, 256, 0, stream>>>(W0, b0, W1, b1, W2, p1, p2,
                                                 t3, hist, u2, v2, w2);
    k_t3<<<256, 256, 0, stream>>>(x, p0, p1, p2, t3);
    k_final<<<NCLS, 128, 0, stream>>>(fc_w, fc_b, b2, u2, v2, w2, hist, t3,
                                      (float*)d_out);
}

// Round 3
// 136.647 us; speedup vs baseline: 1.1895x; 1.1334x over previous
//
#include <hip/hip_runtime.h>

#define IN_FEATURES 212445
#define N1 65536
#define N2 16384
#define NCLS 20
#define BATCH 32
#define HIST_BLOCKS 32
#define MCHUNK 1024
#define MBLOCKS ((IN_FEATURES + MCHUNK - 1) / MCHUNK)   // 208
#define TCHUNK 4096
#define TCHUNKS ((IN_FEATURES + TCHUNK - 1) / TCHUNK)   // 52

// ws layout (bytes):
//  t3    : float[32*128]   @ 0       (16384)  -- zeroed by k_setup block 1
//  hist  : int[32*256]     @ 16384   (32768)  -- per-block partial counts (written)
//  u2    : float[128]      @ 49152
//  v2    : float[128]      @ 49664
//  w2    : float[128]      @ 50176
//  midx  : int[212445]     @ 51200   (849780) -- composed parent chain

// k_setup, grid = 2 + HIST_BLOCKS + MBLOCKS:
//  b=0        : u2 = W2*W1*W0, v2 = W2*W1*b0, w2 = W2*b1
//  b=1        : zero t3
//  b=2..33    : count histograms (c2 over N1 via chain, cnt2 over N2)
//  b=34..241  : midx[i] = p2[p1[p0[i]]]
__global__ __launch_bounds__(256) void k_setup(
    const float* __restrict__ W0, const float* __restrict__ b0,
    const float* __restrict__ W1, const float* __restrict__ b1,
    const float* __restrict__ W2,
    const int* __restrict__ p0, const int* __restrict__ p1,
    const int* __restrict__ p2,
    float* __restrict__ t3, int* __restrict__ hist,
    float* __restrict__ u2, float* __restrict__ v2, float* __restrict__ w2,
    int* __restrict__ midx)
{
    int t = threadIdx.x;
    int b = blockIdx.x;
    if (b == 0) {
        __shared__ float su1[64], sv1[64];
        if (t < 64) {
            float a = 0.f, bb = 0.f;
            for (int c = 0; c < 32; ++c) {
                float w = W1[t * 32 + c];
                a  += w * W0[c];      // W0 is (32,1)
                bb += w * b0[c];
            }
            su1[t] = a; sv1[t] = bb;
        }
        __syncthreads();
        if (t < 128) {
            float a = 0.f, bb = 0.f, c = 0.f;
            for (int j = 0; j < 64; ++j) {
                float w = W2[t * 64 + j];
                a  += w * su1[j];
                bb += w * sv1[j];
                c  += w * b1[j];
            }
            u2[t] = a; v2[t] = bb; w2[t] = c;
        }
    } else if (b == 1) {
        for (int s = t; s < BATCH * 128; s += 256) t3[s] = 0.f;
    } else if (b < 2 + HIST_BLOCKS) {
        __shared__ int hA[128], hB[128];
        if (t < 128) { hA[t] = 0; hB[t] = 0; }
        __syncthreads();
        const int total = N1 + N2;
        const int stride = HIST_BLOCKS * 256;
        for (int idx = (b - 2) * 256 + t; idx < total; idx += stride) {
            if (idx < N1) atomicAdd(&hA[p2[p1[idx]]], 1);
            else          atomicAdd(&hB[p2[idx - N1]], 1);
        }
        __syncthreads();
        hist[(b - 2) * 256 + t] = (t < 128) ? hA[t] : hB[t - 128];
    } else {
        int mb = b - (2 + HIST_BLOCKS);
        int base = mb * MCHUNK;
        #pragma unroll
        for (int u = 0; u < MCHUNK / 256; ++u) {
            int i = base + u * 256 + t;
            if (i < IN_FEATURES) midx[i] = p2[p1[p0[i]]];
        }
    }
}

// k_t3: block = (row, 4096-leaf chunk). Per-wave private 128-bin LDS
// histograms; coalesced x/midx loads with a separated load phase for ILP.
__global__ __launch_bounds__(256) void k_t3(
    const float* __restrict__ x, const int* __restrict__ midx,
    float* __restrict__ t3)
{
    __shared__ float hist[4 * 128];
    int t = threadIdx.x;
    for (int s = t; s < 512; s += 256) hist[s] = 0.f;
    __syncthreads();

    int row   = blockIdx.x & 31;
    int chunk = blockIdx.x >> 5;
    int base  = chunk * TCHUNK;
    const float* xr = x + (size_t)row * IN_FEATURES;
    float* hw = hist + (t >> 6) * 128;

    if (base + TCHUNK <= IN_FEATURES) {
        for (int k = 0; k < TCHUNK / 1024; ++k) {       // 4 outer iters
            float v[4]; int mi[4];
            #pragma unroll
            for (int u = 0; u < 4; ++u) {
                int i = base + (k * 4 + u) * 256 + t;
                v[u]  = xr[i];
                mi[u] = midx[i];
            }
            #pragma unroll
            for (int u = 0; u < 4; ++u)
                atomicAdd(&hw[mi[u]], v[u]);
        }
    } else {
        for (int i = base + t; i < IN_FEATURES; i += 256)
            atomicAdd(&hw[midx[i]], xr[i]);
    }
    __syncthreads();
    if (t < 128) {
        float s = hist[t] + hist[128 + t] + hist[256 + t] + hist[384 + t];
        atomicAdd(&t3[row * 128 + t], s);
    }
}

// k_final, grid = 20 blocks x 256:
//  Sa[m] = sum_o fc_w[cls,o*128+m]*u2[o];  o-loop split across two halves.
//  const = fc_b + sum_m (c2[m]*Sv[m] + cnt2[m]*Sw[m] + Sb[m])
//  out[n,cls] = const + sum_m Sa[m]*t3[n,m]
__global__ __launch_bounds__(256) void k_final(
    const float* __restrict__ fc_w, const float* __restrict__ fc_b,
    const float* __restrict__ b2,
    const float* __restrict__ u2, const float* __restrict__ v2,
    const float* __restrict__ w2,
    const int* __restrict__ hist, const float* __restrict__ t3,
    float* __restrict__ out)
{
    __shared__ float su[128], sv[128], sw[128], sb[128];
    __shared__ float sA[128];
    __shared__ float pA[256], pV[256], pW[256], pB[256];
    __shared__ float red[256];
    __shared__ float st3[BATCH * 129];
    __shared__ float sconst;
    int t = threadIdx.x;
    int m = t & 127, h = t >> 7;
    int cls = blockIdx.x;

    if (h == 0) { su[m] = u2[m]; sv[m] = v2[m]; sw[m] = w2[m]; sb[m] = b2[m]; }
    for (int s = t; s < BATCH * 128; s += 256)
        st3[(s >> 7) * 129 + (s & 127)] = t3[s];
    __syncthreads();

    const float* fw = fc_w + cls * 16384 + m;
    float Sa = 0.f, Sv = 0.f, Sw = 0.f, Sb = 0.f;
    #pragma unroll 8
    for (int o = h * 64; o < h * 64 + 64; ++o) {
        float wv = fw[o * 128];
        Sa += wv * su[o]; Sv += wv * sv[o]; Sw += wv * sw[o]; Sb += wv * sb[o];
    }
    pA[t] = Sa; pV[t] = Sv; pW[t] = Sw; pB[t] = Sb;
    __syncthreads();
    if (h == 0) {
        Sa = pA[m] + pA[128 + m]; Sv = pV[m] + pV[128 + m];
        Sw = pW[m] + pW[128 + m]; Sb = pB[m] + pB[128 + m];
        int c2 = 0, cn2 = 0;
        #pragma unroll
        for (int hb = 0; hb < HIST_BLOCKS; ++hb) {
            c2  += hist[hb * 256 + m];
            cn2 += hist[hb * 256 + 128 + m];
        }
        sA[m] = Sa;
        red[m] = (float)c2 * Sv + (float)cn2 * Sw + Sb;
    }
    __syncthreads();
    for (int s2 = 64; s2 > 0; s2 >>= 1) {
        if (t < s2) red[t] += red[t + s2];
        __syncthreads();
    }
    if (t == 0) sconst = red[0] + fc_b[cls];
    __syncthreads();

    // 32 rows x 8 octants of 16
    int n = t >> 3, oc = t & 7;
    const float* tr = st3 + n * 129 + oc * 16;
    const float* ar = sA + oc * 16;
    float s = 0.f;
    #pragma unroll
    for (int k = 0; k < 16; ++k) s += ar[k] * tr[k];
    red[t] = s;
    __syncthreads();
    if (oc == 0) {
        float tot = sconst;
        #pragma unroll
        for (int k = 0; k < 8; ++k) tot += red[t + k];
        out[n * NCLS + cls] = tot;
    }
}

extern "C" void kernel_launch(void* const* d_in, const int* in_sizes, int n_in,
                              void* d_out, int out_size, void* d_ws, size_t ws_size,
                              hipStream_t stream)
{
    const float* x    = (const float*)d_in[0];
    const float* W0   = (const float*)d_in[1];
    const float* b0   = (const float*)d_in[2];
    const float* W1   = (const float*)d_in[3];
    const float* b1   = (const float*)d_in[4];
    const float* W2   = (const float*)d_in[5];
    const float* b2   = (const float*)d_in[6];
    const float* fc_w = (const float*)d_in[7];
    const float* fc_b = (const float*)d_in[8];
    const int*   p0   = (const int*)d_in[9];
    const int*   p1   = (const int*)d_in[10];
    const int*   p2   = (const int*)d_in[11];

    char* ws = (char*)d_ws;
    float* t3   = (float*)(ws + 0);
    int*   hist = (int*)(ws + 16384);
    float* u2   = (float*)(ws + 49152);
    float* v2   = (float*)(ws + 49664);
    float* w2   = (float*)(ws + 50176);
    int*   midx = (int*)(ws + 51200);

    k_setup<<<2 + HIST_BLOCKS + MBLOCKS, 256, 0, stream>>>(
        W0, b0, W1, b1, W2, p0, p1, p2, t3, hist, u2, v2, w2, midx);
    k_t3<<<BATCH * TCHUNKS, 256, 0, stream>>>(x, midx, t3);
    k_final<<<NCLS, 256, 0, stream>>>(fc_w, fc_b, b2, u2, v2, w2, hist, t3,
                                      (float*)d_out);
}